// Round 17
// baseline (94.595 us; speedup 1.0000x reference)
//
#include <hip/hip_runtime.h>
#include <math.h>

#define NW 599
#define NRR 598

__device__ inline float wave_sum(float v) {
#pragma unroll
  for (int o = 32; o > 0; o >>= 1) v += __shfl_down(v, o);
  return v;
}

// One block per row, 640 threads (10 waves). Phase 1: each thread computes one
// window's softargmax straight from global memory into registers (no LDS for
// x; L1 serves the 2x overlap between neighboring windows). Phase 2: thread n
// owns rr[n]; 27 reductions via wave shuffles + LDS partials; MLP+LN in wave 0.
__global__ __launch_bounds__(640, 6) void prv_row(
    const float* __restrict__ x, const float* __restrict__ W1,
    const float* __restrict__ b1, const float* __restrict__ W2,
    const float* __restrict__ b2, const float* __restrict__ gamma,
    const float* __restrict__ beta, float* __restrict__ out) {
  __shared__ float s_pk[600];
  __shared__ float s_part[10][27];
  __shared__ float s_tot[27];
  __shared__ float s_feat[5];

  const int row = blockIdx.x;
  const int tid = threadIdx.x;
  const int wv = tid >> 6, lane = tid & 63;

  // ---------- phase 1: softargmax peaks, register-direct ----------
  if (tid < NW) {
    const float* __restrict__ p = x + (size_t)row * 9000 + 15 * tid;
    float v[30];
#pragma unroll
    for (int j = 0; j < 30; ++j) v[j] = p[j];
    float m = v[0];
#pragma unroll
    for (int j = 1; j < 30; ++j) m = fmaxf(m, v[j]);
    float se = 0.f, we = 0.f;
#pragma unroll
    for (int j = 0; j < 30; ++j) {
      float e = __expf((v[j] - m) * 10.0f);  // temp = 0.1
      se += e;
      we = fmaf((float)j, e, we);
    }
    s_pk[tid] = we / se + 15.0f * (float)tid;
  }
  __syncthreads();

  // ---------- phase 2: per-thread rr contribution ----------
  const float inv30 = 1.0f / 30.0f;
  float rv = 0.f, rv2 = 0.f, d2 = 0.f;
  if (tid < NRR) {
    rv = (s_pk[tid + 1] - s_pk[tid]) * inv30;
    rv2 = rv * rv;
    if (tid < NRR - 1) {
      float d = (s_pk[tid + 2] - 2.f * s_pk[tid + 1] + s_pk[tid]) * inv30;
      d2 = d * d;
    }
  }

  // DFT bins k=2..13 of rfft(rr,1024): this thread contributes rv*e^{-i...}
  const float c0 = 6.13592315154256491e-3f;  // 2*pi/1024
  float re[12], im[12];
#pragma unroll
  for (int kk = 0; kk < 12; ++kk) {
    const int mph = ((kk + 2) * tid) & 1023;  // exact integer phase
    float sn, cs;
    __sincosf((float)mph * c0, &sn, &cs);
    re[kk] = rv * cs;
    im[kk] = -rv * sn;
  }

  // ---------- 27 block reductions: wave shuffle + LDS partials ----------
  {
    float a = wave_sum(rv);
    float b = wave_sum(rv2);
    float c = wave_sum(d2);
    if (lane == 0) {
      s_part[wv][0] = a;
      s_part[wv][1] = b;
      s_part[wv][2] = c;
    }
  }
#pragma unroll
  for (int kk = 0; kk < 12; ++kk) {
    float a = wave_sum(re[kk]);
    float b = wave_sum(im[kk]);
    if (lane == 0) {
      s_part[wv][3 + 2 * kk] = a;
      s_part[wv][4 + 2 * kk] = b;
    }
  }
  __syncthreads();
  if (tid < 27) {
    float t = 0.f;
#pragma unroll
    for (int w = 0; w < 10; ++w) t += s_part[w][tid];
    s_tot[tid] = t;
  }
  __syncthreads();
  if (tid == 0) {
    const float S = s_tot[0], S2 = s_tot[1], D2 = s_tot[2];
    const float mean = S * (1.0f / (float)NRR);
    const float var =
        (S2 - (float)NRR * mean * mean) * (1.0f / (float)(NRR - 1));
    float lf = 0.f, hf = 0.f;
#pragma unroll
    for (int kk = 0; kk < 12; ++kk) {
      float r = s_tot[3 + 2 * kk], i2 = s_tot[4 + 2 * kk];
      float pw = fmaf(r, r, i2 * i2);
      if (kk < 4) lf += pw; else hf += pw;
    }
    s_feat[0] = mean;
    s_feat[1] = sqrtf(D2 * (1.0f / (float)(NRR - 1)) + 1e-6f);  // rmssd
    s_feat[2] = sqrtf(fmaxf(var, 0.f));                          // sdnn
    s_feat[3] = lf;
    s_feat[4] = hf;
  }
  __syncthreads();

  // ---------- MLP (5->64->128) + LayerNorm in wave 0 ----------
  if (wv == 0) {
    const float f0 = s_feat[0], f1 = s_feat[1], f2 = s_feat[2],
                f3 = s_feat[3], f4 = s_feat[4];
    float h1 = b1[lane];
    h1 = fmaf(f0, W1[lane], h1);
    h1 = fmaf(f1, W1[64 + lane], h1);
    h1 = fmaf(f2, W1[128 + lane], h1);
    h1 = fmaf(f3, W1[192 + lane], h1);
    h1 = fmaf(f4, W1[256 + lane], h1);
    h1 = fmaxf(h1, 0.f);

    float a0 = b2[lane], a1 = b2[64 + lane];
#pragma unroll 8
    for (int i = 0; i < 64; ++i) {
      float hv = __shfl(h1, i);
      a0 = fmaf(hv, W2[i * 128 + lane], a0);
      a1 = fmaf(hv, W2[i * 128 + 64 + lane], a1);
    }

    float mu = a0 + a1;
#pragma unroll
    for (int o = 32; o > 0; o >>= 1) mu += __shfl_xor(mu, o);
    mu *= (1.0f / 128.0f);
    float vv = (a0 - mu) * (a0 - mu) + (a1 - mu) * (a1 - mu);
#pragma unroll
    for (int o = 32; o > 0; o >>= 1) vv += __shfl_xor(vv, o);
    vv *= (1.0f / 128.0f);
    const float inv = rsqrtf(vv + 1e-5f);
    out[(size_t)row * 128 + lane] = (a0 - mu) * inv * gamma[lane] + beta[lane];
    out[(size_t)row * 128 + 64 + lane] =
        (a1 - mu) * inv * gamma[64 + lane] + beta[64 + lane];
  }
}

extern "C" void kernel_launch(void* const* d_in, const int* in_sizes, int n_in,
                              void* d_out, int out_size, void* d_ws,
                              size_t ws_size, hipStream_t stream) {
  const float* x = (const float*)d_in[0];
  const float* W1 = (const float*)d_in[1];
  const float* b1 = (const float*)d_in[2];
  const float* W2 = (const float*)d_in[3];
  const float* b2 = (const float*)d_in[4];
  const float* gamma = (const float*)d_in[5];
  const float* beta = (const float*)d_in[6];
  float* out = (float*)d_out;

  const int B = in_sizes[0] / 9000;
  prv_row<<<B, 640, 0, stream>>>(x, W1, b1, W2, b2, gamma, beta, out);
}